// Round 20
// baseline (295.915 us; speedup 1.0000x reference)
//
#include <hip/hip_runtime.h>

typedef _Float16 f16;
typedef _Float16 f16x4 __attribute__((ext_vector_type(4)));
typedef _Float16 f16x8 __attribute__((ext_vector_type(8)));
typedef float    f32x4 __attribute__((ext_vector_type(4)));

#define B_ 4
#define T_ 2048
#define C_ 1024
#define H_ 16
#define D_ 64

#if __has_builtin(__builtin_amdgcn_exp2f)
#define FAST_EXP(x) __builtin_amdgcn_exp2f(x)
#define QSCALE (0.125f * 1.44269504f)
#define POFF 8.0f
#else
#define FAST_EXP(x) __expf(x)
#define QSCALE 0.125f
#define POFF 5.5452f
#endif

__device__ __forceinline__ void gload_lds16(const f16* g, f16* l) {
  __builtin_amdgcn_global_load_lds(
      (const __attribute__((address_space(1))) unsigned int*)g,
      (__attribute__((address_space(3))) unsigned int*)l, 16, 0, 0);
}

// -------- fused prep: x->f16 cvt + both weight transposes, ONE launch --------
__global__ void prep_kernel(const float* __restrict__ x, f16* __restrict__ xb,
                            const float* __restrict__ Wqkv, f16* __restrict__ WqkvT,
                            const float* __restrict__ Wout, f16* __restrict__ WoutT) {
  int bx = blockIdx.x, by = blockIdx.y;
  if (bx >= 128) {  // cvt branch
    const int n4 = (B_ * T_ * C_) / 4;
    int i = ((bx - 128) * 32 + by) * 256 + threadIdx.x;
    const int stride = 64 * 32 * 256;
    #pragma unroll 4
    for (; i < n4; i += stride) {
      float4 v = ((const float4*)x)[i];
      f16x4 h = { (f16)v.x, (f16)v.y, (f16)v.z, (f16)v.w };
      ((f16x4*)xb)[i] = h;
    }
    return;
  }
  __shared__ f16 tile[32][33];
  const int K = 1024;
  const float* W; f16* Wt; int N;
  if (bx < 96) { W = Wqkv; Wt = WqkvT; N = 3072; }
  else         { W = Wout; Wt = WoutT; N = 1024; bx -= 96; }
  int tx = threadIdx.x & 31, ty = threadIdx.x >> 5;
  #pragma unroll
  for (int i = ty; i < 32; i += 8)
    tile[i][tx] = (f16)W[(size_t)(by * 32 + i) * N + bx * 32 + tx];
  __syncthreads();
  #pragma unroll
  for (int i = ty; i < 32; i += 8)
    Wt[(size_t)(bx * 32 + i) * K + by * 32 + tx] = tile[tx][i];
}

// ---------------- 128^2 GEMM (R17-proven, conflict-free swizzle) --------------
template <int EPI>
__global__ __launch_bounds__(256, 3)
void gemm_kernel(const f16* __restrict__ A, const f16* __restrict__ Bt,
                 const float* __restrict__ bias, float* __restrict__ outF,
                 f16* __restrict__ q, f16* __restrict__ kk, f16* __restrict__ vt,
                 int M, int N, int K) {
  __shared__ __align__(16) f16 As[3][128 * 32];
  __shared__ __align__(16) f16 Bs[3][128 * 32];
  const int nbn = N >> 7;
  const int bid = blockIdx.x;
  const int bm = bid / nbn, bn = bid % nbn;
  const int m0 = bm << 7, n0 = bn << 7;
  const int tid = threadIdx.x;
  const int lane = tid & 63, wid = tid >> 6;
  const int wr = wid >> 1, wc = wid & 1;

  f32x4 acc[4][4] = {};

  const int srow = lane >> 2;
  const int scol = (((lane & 3) ^ ((lane >> 3) & 3)) << 3);
  const f16* Abase = A + (size_t)(m0 + srow) * K + scol;
  const f16* Bbase = Bt + (size_t)(n0 + srow) * K + scol;

  auto stage = [&](int buf, int kt) {
    const int c0 = wid * 2;
    #pragma unroll
    for (int c = c0; c < c0 + 2; ++c) {
      gload_lds16(Abase + (size_t)c * 16 * K + kt * 32, &As[buf][c * 512]);
      gload_lds16(Bbase + (size_t)c * 16 * K + kt * 32, &Bs[buf][c * 512]);
    }
  };

  const int g = lane >> 4;
  const int rr = lane & 15;
  const int swz = (g ^ ((rr >> 1) & 3)) << 4;

  auto compute = [&](int buf) {
    f16x8 af[4], bf[4];
    #pragma unroll
    for (int t = 0; t < 4; ++t) {
      af[t] = *(const f16x8*)((const char*)&As[buf][0] + (wr * 64 + t * 16 + rr) * 64 + swz);
      bf[t] = *(const f16x8*)((const char*)&Bs[buf][0] + (wc * 64 + t * 16 + rr) * 64 + swz);
    }
    __builtin_amdgcn_s_setprio(1);
    #pragma unroll
    for (int i = 0; i < 4; ++i)
      #pragma unroll
      for (int j = 0; j < 4; ++j)
        acc[i][j] = __builtin_amdgcn_mfma_f32_16x16x32_f16(af[i], bf[j], acc[i][j], 0, 0, 0);
    __builtin_amdgcn_s_setprio(0);
  };

  const int nk = K >> 5;
  int bcur = 0, bnext = 1, bnn = 2;
  stage(0, 0);
  stage(1, 1);
  asm volatile("s_waitcnt vmcnt(4)" ::: "memory");
  __builtin_amdgcn_s_barrier();
  __builtin_amdgcn_sched_barrier(0);
  for (int t = 0; t < nk; ++t) {
    if (t + 2 < nk) stage(bnn, t + 2);
    compute(bcur);
    if (t + 1 < nk) {
      if (t + 2 < nk) asm volatile("s_waitcnt vmcnt(4)" ::: "memory");
      else            asm volatile("s_waitcnt vmcnt(0)" ::: "memory");
      __builtin_amdgcn_s_barrier();
      __builtin_amdgcn_sched_barrier(0);
    }
    const int tmp = bcur; bcur = bnext; bnext = bnn; bnn = tmp;
  }

  const int col = lane & 15;
  const int row4 = (lane >> 4) << 2;
  #pragma unroll
  for (int i = 0; i < 4; ++i) {
    #pragma unroll
    for (int j = 0; j < 4; ++j) {
      const int n = n0 + wc * 64 + j * 16 + col;
      const float bn_ = bias[n];
      #pragma unroll
      for (int r = 0; r < 4; ++r) {
        const int m = m0 + wr * 64 + i * 16 + row4 + r;
        const float v = acc[i][j][r] + bn_;
        if (EPI == 1) {
          outF[(size_t)m * N + n] = v;
        } else {
          const int which = n >> 10;           // 0=q 1=k 2=v
          const int cc = n & 1023;
          const int h = cc >> 6, d = cc & 63;
          const int b = m >> 11, t = m & 2047;
          const size_t bh = (size_t)b * 16 + h;
          const f16 hv = (f16)v;
          if (which == 0)      q [(bh * T_ + t) * D_ + d] = hv;
          else if (which == 1) kk[(bh * T_ + t) * D_ + d] = hv;
          else                 vt[(bh * D_ + d) * T_ + t] = hv;  // V transposed
        }
      }
    }
  }
}

// ------ causal flash attention: V direct from L2, 32KB LDS -> 4 blocks/CU ------
// K staged (dbuf, swizzled); V^T read per-lane from global (XCD-L2-resident:
// 8 bh x 512KB = 4MB/XCD). 1024 blocks LPT-ordered. Fixed-base softmax.
__global__ __launch_bounds__(256, 4)
void attn_kernel(const f16* __restrict__ Q, const f16* __restrict__ Kg,
                 const f16* __restrict__ Vt, f16* __restrict__ Aout) {
  __shared__ __align__(16) f16 Ks[2][64 * 64];   // 16KB
  __shared__ __align__(16) f16 Pt[4][32 * 64];   // 16KB

  const int bid = blockIdx.x;
  const int xcd = bid & 7, k = bid >> 3;
  const int bh = (xcd << 3) + (k & 7);
  const int ti = 15 - (k >> 3);
  const int lane = threadIdx.x & 63, w = threadIdx.x >> 6;
  const int col = lane & 15;
  const int g = lane >> 4;
  const int ko = g << 3;

  const f16* Qp = Q + (size_t)bh * T_ * D_;
  const f16* Kp = Kg + (size_t)bh * T_ * D_;
  const f16* Vp = Vt + (size_t)bh * D_ * T_;

  const int sr = lane >> 3;
  const int sc = ((lane & 7) ^ (sr & 7)) << 3;

  auto stage = [&](int buf, int kb) {
    #pragma unroll
    for (int c2 = 0; c2 < 2; ++c2) {
      const int c = (w << 1) + c2;
      gload_lds16(Kp + (size_t)(kb + (c << 3) + sr) * D_ + sc, &Ks[buf][c * 512]);
    }
  };
  auto ldsK = [&](int buf, int krow, int d0) -> f16x8 {
    const int off = krow * 128 + ((d0 << 1) ^ ((krow & 7) << 4));
    return *(const f16x8*)((const char*)&Ks[buf][0] + off);
  };

  char* PtW = (char*)&Pt[w][0];
  const int b = bh >> 4, hd = bh & 15;

  const int qrow0 = (ti << 7) + (w << 5);
  const int nkt = (ti << 1) + 2;

  const f16 qsc = (f16)QSCALE;
  f16x8 qf[2][2];
  #pragma unroll
  for (int h = 0; h < 2; ++h)
    #pragma unroll
    for (int s = 0; s < 2; ++s) {
      f16x8 t = *(const f16x8*)&Qp[(size_t)(qrow0 + h * 16 + col) * D_ + s * 32 + ko];
      #pragma unroll
      for (int e = 0; e < 8; ++e) t[e] = t[e] * qsc;
      qf[h][s] = t;
    }

  f32x4 o[2][4] = {};
  f32x4 lpv[2] = {};

  auto COMPUTE = [&](int buf, int kb) {
    f32x4 sc2[2][4] = {};
    __builtin_amdgcn_s_setprio(1);
    #pragma unroll
    for (int s = 0; s < 2; ++s)
      #pragma unroll
      for (int mt = 0; mt < 4; ++mt) {
        f16x8 kf = ldsK(buf, mt * 16 + col, s * 32 + ko);
        sc2[0][mt] = __builtin_amdgcn_mfma_f32_16x16x32_f16(kf, qf[0][s], sc2[0][mt], 0, 0, 0);
        sc2[1][mt] = __builtin_amdgcn_mfma_f32_16x16x32_f16(kf, qf[1][s], sc2[1][mt], 0, 0, 0);
      }
    __builtin_amdgcn_s_setprio(0);

    // prefetch V fragments from global (L2-resident) while softmax runs
    f16x8 vfr[2][4];
    #pragma unroll
    for (int s = 0; s < 2; ++s)
      #pragma unroll
      for (int mt = 0; mt < 4; ++mt)
        vfr[s][mt] = *(const f16x8*)&Vp[(size_t)(mt * 16 + col) * T_ + kb + s * 32 + ko];

    if (kb + 63 > qrow0) {
      #pragma unroll
      for (int mt = 0; mt < 4; ++mt)
        #pragma unroll
        for (int r = 0; r < 4; ++r) {
          const int kv = kb + mt * 16 + (g << 2) + r;
          if (kv > qrow0 + col)      sc2[0][mt][r] = -1e30f;
          if (kv > qrow0 + 16 + col) sc2[1][mt][r] = -1e30f;
        }
    }

    #pragma unroll
    for (int h = 0; h < 2; ++h) {
      #pragma unroll
      for (int mt = 0; mt < 4; ++mt) {
        f16x4 ph;
        #pragma unroll
        for (int r = 0; r < 4; ++r) {
          const float p = FAST_EXP(sc2[h][mt][r] - POFF);
          lpv[h][r] += p;
          ph[r] = (f16)p;
        }
        *(f16x4*)(PtW + (h * 16 + col) * 128 + (((mt << 5) + (g << 3)) ^ ((col & 7) << 4))) = ph;
      }
    }

    __builtin_amdgcn_s_setprio(1);
    #pragma unroll
    for (int s = 0; s < 2; ++s) {
      const int pcb = ((s << 6) + (g << 4)) ^ ((col & 7) << 4);
      f16x8 pb0 = *(const f16x8*)(PtW + col * 128 + pcb);
      f16x8 pb1 = *(const f16x8*)(PtW + (16 + col) * 128 + pcb);
      #pragma unroll
      for (int mt = 0; mt < 4; ++mt) {
        o[0][mt] = __builtin_amdgcn_mfma_f32_16x16x32_f16(vfr[s][mt], pb0, o[0][mt], 0, 0, 0);
        o[1][mt] = __builtin_amdgcn_mfma_f32_16x16x32_f16(vfr[s][mt], pb1, o[1][mt], 0, 0, 0);
      }
    }
    __builtin_amdgcn_s_setprio(0);
  };

  stage(0, 0);
  asm volatile("s_waitcnt vmcnt(0)" ::: "memory");
  __builtin_amdgcn_s_barrier();
  __builtin_amdgcn_sched_barrier(0);

  #pragma unroll 1
  for (int kt = 0; kt < nkt; ++kt) {
    if (kt + 1 < nkt) stage((kt + 1) & 1, (kt + 1) << 6);
    if ((kt << 6) <= qrow0 + 31) COMPUTE(kt & 1, kt << 6);

    __builtin_amdgcn_sched_barrier(0);
    asm volatile("s_waitcnt vmcnt(0)" ::: "memory");
    __builtin_amdgcn_s_barrier();
    __builtin_amdgcn_sched_barrier(0);
  }

  #pragma unroll
  for (int h = 0; h < 2; ++h) {
    float l = lpv[h][0] + lpv[h][1] + lpv[h][2] + lpv[h][3];
    l += __shfl_xor(l, 16, 64);
    l += __shfl_xor(l, 32, 64);
    const float inv = 1.0f / l;
    const int t = qrow0 + h * 16 + col;
    const size_t rowoff = ((size_t)b * T_ + t) * C_ + (size_t)hd * D_;
    #pragma unroll
    for (int mt = 0; mt < 4; ++mt) {
      f16x4 ov;
      #pragma unroll
      for (int r = 0; r < 4; ++r) ov[r] = (f16)(o[h][mt][r] * inv);
      *(f16x4*)&Aout[rowoff + mt * 16 + (g << 2)] = ov;
    }
  }
}

// ---------------- launch ----------------
extern "C" void kernel_launch(void* const* d_in, const int* in_sizes, int n_in,
                              void* d_out, int out_size, void* d_ws, size_t ws_size,
                              hipStream_t stream) {
  const float* x    = (const float*)d_in[0];
  const float* Wqkv = (const float*)d_in[1];
  const float* bqkv = (const float*)d_in[2];
  const float* Wout = (const float*)d_in[3];
  const float* bout = (const float*)d_in[4];
  float* out = (float*)d_out;

  char* ws = (char*)d_ws;
  f16* xb     = (f16*)ws;                   // 16MB (x in f16; later reused as Aout)
  f16* Wqkv_t = (f16*)(ws + (16u << 20));   // 6MB  [3072,1024]
  f16* Wout_t = (f16*)(ws + (22u << 20));   // 2MB  [1024,1024]
  f16* Qb     = (f16*)(ws + (24u << 20));   // 16MB [B,H,T,D]
  f16* Kb     = (f16*)(ws + (40u << 20));   // 16MB [B,H,T,D]
  f16* Vtb    = (f16*)(ws + (56u << 20));   // 16MB [B,H,D,T]

  dim3 gp(192, 32);
  prep_kernel<<<gp, 256, 0, stream>>>(x, xb, Wqkv, Wqkv_t, Wout, Wout_t);

  gemm_kernel<0><<<64 * 24, 256, 0, stream>>>(xb, Wqkv_t, bqkv, nullptr,
                                              Qb, Kb, Vtb, 8192, 3072, 1024);
  attn_kernel<<<1024, 256, 0, stream>>>(Qb, Kb, Vtb, xb /*Aout alias*/);
  gemm_kernel<1><<<64 * 8, 256, 0, stream>>>(xb, Wout_t, bout, out,
                                             nullptr, nullptr, nullptr, 8192, 1024, 1024);
}

// Round 21
// 187.231 us; speedup vs baseline: 1.5805x; 1.5805x over previous
//
#include <hip/hip_runtime.h>

typedef _Float16 f16;
typedef _Float16 f16x4 __attribute__((ext_vector_type(4)));
typedef _Float16 f16x8 __attribute__((ext_vector_type(8)));
typedef float    f32x4 __attribute__((ext_vector_type(4)));

#define B_ 4
#define T_ 2048
#define C_ 1024
#define H_ 16
#define D_ 64

#if __has_builtin(__builtin_amdgcn_exp2f)
#define FAST_EXP(x) __builtin_amdgcn_exp2f(x)
#define QSCALE (0.125f * 1.44269504f)
#define POFF 8.0f
#else
#define FAST_EXP(x) __expf(x)
#define QSCALE 0.125f
#define POFF 5.5452f
#endif

__device__ __forceinline__ void gload_lds16(const f16* g, f16* l) {
  __builtin_amdgcn_global_load_lds(
      (const __attribute__((address_space(1))) unsigned int*)g,
      (__attribute__((address_space(3))) unsigned int*)l, 16, 0, 0);
}

// -------- fused prep: x->f16 cvt + both weight transposes, ONE launch --------
// grid (192,32): bx<96 Wqkv transpose; 96<=bx<128 Wout transpose; bx>=128 cvt.
__global__ void prep_kernel(const float* __restrict__ x, f16* __restrict__ xb,
                            const float* __restrict__ Wqkv, f16* __restrict__ WqkvT,
                            const float* __restrict__ Wout, f16* __restrict__ WoutT) {
  int bx = blockIdx.x, by = blockIdx.y;
  if (bx >= 128) {  // cvt branch: 64x32 blocks, grid-stride over 2097152 float4
    const int n4 = (B_ * T_ * C_) / 4;
    int i = ((bx - 128) * 32 + by) * 256 + threadIdx.x;
    const int stride = 64 * 32 * 256;
    #pragma unroll 4
    for (; i < n4; i += stride) {
      float4 v = ((const float4*)x)[i];
      f16x4 h = { (f16)v.x, (f16)v.y, (f16)v.z, (f16)v.w };
      ((f16x4*)xb)[i] = h;
    }
    return;
  }
  __shared__ f16 tile[32][33];
  const int K = 1024;
  const float* W; f16* Wt; int N;
  if (bx < 96) { W = Wqkv; Wt = WqkvT; N = 3072; }
  else         { W = Wout; Wt = WoutT; N = 1024; bx -= 96; }
  int tx = threadIdx.x & 31, ty = threadIdx.x >> 5;
  #pragma unroll
  for (int i = ty; i < 32; i += 8)
    tile[i][tx] = (f16)W[(size_t)(by * 32 + i) * N + bx * 32 + tx];
  __syncthreads();
  #pragma unroll
  for (int i = ty; i < 32; i += 8)
    Wt[(size_t)(bx * 32 + i) * K + by * 32 + tx] = tile[tx][i];
}

// ---------------- 128^2 GEMM (R17-proven, conflict-free swizzle) --------------
template <int EPI>
__global__ __launch_bounds__(256, 3)
void gemm_kernel(const f16* __restrict__ A, const f16* __restrict__ Bt,
                 const float* __restrict__ bias, float* __restrict__ outF,
                 f16* __restrict__ q, f16* __restrict__ kk, f16* __restrict__ vt,
                 int M, int N, int K) {
  __shared__ __align__(16) f16 As[3][128 * 32];
  __shared__ __align__(16) f16 Bs[3][128 * 32];
  const int nbn = N >> 7;
  const int bid = blockIdx.x;
  const int bm = bid / nbn, bn = bid % nbn;
  const int m0 = bm << 7, n0 = bn << 7;
  const int tid = threadIdx.x;
  const int lane = tid & 63, wid = tid >> 6;
  const int wr = wid >> 1, wc = wid & 1;

  f32x4 acc[4][4] = {};

  const int srow = lane >> 2;
  const int scol = (((lane & 3) ^ ((lane >> 3) & 3)) << 3);
  const f16* Abase = A + (size_t)(m0 + srow) * K + scol;
  const f16* Bbase = Bt + (size_t)(n0 + srow) * K + scol;

  auto stage = [&](int buf, int kt) {
    const int c0 = wid * 2;
    #pragma unroll
    for (int c = c0; c < c0 + 2; ++c) {
      gload_lds16(Abase + (size_t)c * 16 * K + kt * 32, &As[buf][c * 512]);
      gload_lds16(Bbase + (size_t)c * 16 * K + kt * 32, &Bs[buf][c * 512]);
    }
  };

  const int g = lane >> 4;
  const int rr = lane & 15;
  const int swz = (g ^ ((rr >> 1) & 3)) << 4;

  auto compute = [&](int buf) {
    f16x8 af[4], bf[4];
    #pragma unroll
    for (int t = 0; t < 4; ++t) {
      af[t] = *(const f16x8*)((const char*)&As[buf][0] + (wr * 64 + t * 16 + rr) * 64 + swz);
      bf[t] = *(const f16x8*)((const char*)&Bs[buf][0] + (wc * 64 + t * 16 + rr) * 64 + swz);
    }
    __builtin_amdgcn_s_setprio(1);
    #pragma unroll
    for (int i = 0; i < 4; ++i)
      #pragma unroll
      for (int j = 0; j < 4; ++j)
        acc[i][j] = __builtin_amdgcn_mfma_f32_16x16x32_f16(af[i], bf[j], acc[i][j], 0, 0, 0);
    __builtin_amdgcn_s_setprio(0);
  };

  const int nk = K >> 5;
  int bcur = 0, bnext = 1, bnn = 2;
  stage(0, 0);
  stage(1, 1);
  asm volatile("s_waitcnt vmcnt(4)" ::: "memory");
  __builtin_amdgcn_s_barrier();
  __builtin_amdgcn_sched_barrier(0);
  for (int t = 0; t < nk; ++t) {
    if (t + 2 < nk) stage(bnn, t + 2);
    compute(bcur);
    if (t + 1 < nk) {
      if (t + 2 < nk) asm volatile("s_waitcnt vmcnt(4)" ::: "memory");
      else            asm volatile("s_waitcnt vmcnt(0)" ::: "memory");
      __builtin_amdgcn_s_barrier();
      __builtin_amdgcn_sched_barrier(0);
    }
    const int tmp = bcur; bcur = bnext; bnext = bnn; bnn = tmp;
  }

  const int col = lane & 15;
  const int row4 = (lane >> 4) << 2;
  #pragma unroll
  for (int i = 0; i < 4; ++i) {
    #pragma unroll
    for (int j = 0; j < 4; ++j) {
      const int n = n0 + wc * 64 + j * 16 + col;
      const float bn_ = bias[n];
      #pragma unroll
      for (int r = 0; r < 4; ++r) {
        const int m = m0 + wr * 64 + i * 16 + row4 + r;
        const float v = acc[i][j][r] + bn_;
        if (EPI == 1) {
          outF[(size_t)m * N + n] = v;
        } else {
          const int which = n >> 10;           // 0=q 1=k 2=v
          const int cc = n & 1023;
          const int h = cc >> 6, d = cc & 63;
          const int b = m >> 11, t = m & 2047;
          const size_t bh = (size_t)b * 16 + h;
          const f16 hv = (f16)v;
          if (which == 0)      q [(bh * T_ + t) * D_ + d] = hv;
          else if (which == 1) kk[(bh * T_ + t) * D_ + d] = hv;
          else                 vt[(bh * D_ + d) * T_ + t] = hv;  // V transposed
        }
      }
    }
  }
}

// ---------------- causal flash attention: 1024 blocks, LPT order, 3/CU --------
__global__ __launch_bounds__(256, 3)
void attn_kernel(const f16* __restrict__ Q, const f16* __restrict__ Kg,
                 const f16* __restrict__ Vt, f16* __restrict__ Aout) {
  __shared__ __align__(16) f16 Ks[2][64 * 64];
  __shared__ __align__(16) f16 Vs[2][64 * 64];
  __shared__ __align__(16) f16 Pt[4][32 * 64];

  const int bid = blockIdx.x;
  const int xcd = bid & 7, k = bid >> 3;
  const int bh = (xcd << 3) + (k & 7);
  const int ti = 15 - (k >> 3);
  const int lane = threadIdx.x & 63, w = threadIdx.x >> 6;
  const int col = lane & 15;
  const int g = lane >> 4;
  const int ko = g << 3;

  const f16* Qp = Q + (size_t)bh * T_ * D_;
  const f16* Kp = Kg + (size_t)bh * T_ * D_;
  const f16* Vp = Vt + (size_t)bh * D_ * T_;

  const int sr = lane >> 3;
  const int sc = ((lane & 7) ^ (sr & 7)) << 3;

  auto stage = [&](int buf, int kb) {
    #pragma unroll
    for (int c2 = 0; c2 < 2; ++c2) {
      const int c = (w << 1) + c2;
      gload_lds16(Kp + (size_t)(kb + (c << 3) + sr) * D_ + sc, &Ks[buf][c * 512]);
      gload_lds16(Vp + (size_t)((c << 3) + sr) * T_ + kb + sc, &Vs[buf][c * 512]);
    }
  };
  auto ldsK = [&](int buf, int krow, int d0) -> f16x8 {
    const int off = krow * 128 + ((d0 << 1) ^ ((krow & 7) << 4));
    return *(const f16x8*)((const char*)&Ks[buf][0] + off);
  };
  auto ldsV = [&](int buf, int drow, int k0) -> f16x8 {
    const int off = drow * 128 + ((k0 << 1) ^ ((drow & 7) << 4));
    return *(const f16x8*)((const char*)&Vs[buf][0] + off);
  };

  char* PtW = (char*)&Pt[w][0];
  const int b = bh >> 4, hd = bh & 15;

  const int qrow0 = (ti << 7) + (w << 5);
  const int nkt = (ti << 1) + 2;

  const f16 qsc = (f16)QSCALE;
  f16x8 qf[2][2];
  #pragma unroll
  for (int h = 0; h < 2; ++h)
    #pragma unroll
    for (int s = 0; s < 2; ++s) {
      f16x8 t = *(const f16x8*)&Qp[(size_t)(qrow0 + h * 16 + col) * D_ + s * 32 + ko];
      #pragma unroll
      for (int e = 0; e < 8; ++e) t[e] = t[e] * qsc;
      qf[h][s] = t;
    }

  f32x4 o[2][4] = {};
  f32x4 lpv[2] = {};

  auto COMPUTE = [&](int buf, int kb) {
    f32x4 sc2[2][4] = {};
    __builtin_amdgcn_s_setprio(1);
    #pragma unroll
    for (int s = 0; s < 2; ++s)
      #pragma unroll
      for (int mt = 0; mt < 4; ++mt) {
        f16x8 kf = ldsK(buf, mt * 16 + col, s * 32 + ko);
        sc2[0][mt] = __builtin_amdgcn_mfma_f32_16x16x32_f16(kf, qf[0][s], sc2[0][mt], 0, 0, 0);
        sc2[1][mt] = __builtin_amdgcn_mfma_f32_16x16x32_f16(kf, qf[1][s], sc2[1][mt], 0, 0, 0);
      }
    __builtin_amdgcn_s_setprio(0);

    if (kb + 63 > qrow0) {
      #pragma unroll
      for (int mt = 0; mt < 4; ++mt)
        #pragma unroll
        for (int r = 0; r < 4; ++r) {
          const int kv = kb + mt * 16 + (g << 2) + r;
          if (kv > qrow0 + col)      sc2[0][mt][r] = -1e30f;
          if (kv > qrow0 + 16 + col) sc2[1][mt][r] = -1e30f;
        }
    }

    #pragma unroll
    for (int h = 0; h < 2; ++h) {
      #pragma unroll
      for (int mt = 0; mt < 4; ++mt) {
        f16x4 ph;
        #pragma unroll
        for (int r = 0; r < 4; ++r) {
          const float p = FAST_EXP(sc2[h][mt][r] - POFF);
          lpv[h][r] += p;
          ph[r] = (f16)p;
        }
        *(f16x4*)(PtW + (h * 16 + col) * 128 + (((mt << 5) + (g << 3)) ^ ((col & 7) << 4))) = ph;
      }
    }

    __builtin_amdgcn_s_setprio(1);
    #pragma unroll
    for (int s = 0; s < 2; ++s) {
      const int pcb = ((s << 6) + (g << 4)) ^ ((col & 7) << 4);
      f16x8 pb0 = *(const f16x8*)(PtW + col * 128 + pcb);
      f16x8 pb1 = *(const f16x8*)(PtW + (16 + col) * 128 + pcb);
      #pragma unroll
      for (int mt = 0; mt < 4; ++mt) {
        f16x8 vf = ldsV(buf, mt * 16 + col, s * 32 + ko);
        o[0][mt] = __builtin_amdgcn_mfma_f32_16x16x32_f16(vf, pb0, o[0][mt], 0, 0, 0);
        o[1][mt] = __builtin_amdgcn_mfma_f32_16x16x32_f16(vf, pb1, o[1][mt], 0, 0, 0);
      }
    }
    __builtin_amdgcn_s_setprio(0);
  };

  stage(0, 0);
  asm volatile("s_waitcnt vmcnt(0)" ::: "memory");
  __builtin_amdgcn_s_barrier();
  __builtin_amdgcn_sched_barrier(0);

  #pragma unroll 1
  for (int kt = 0; kt < nkt; ++kt) {
    if (kt + 1 < nkt) stage((kt + 1) & 1, (kt + 1) << 6);
    if ((kt << 6) <= qrow0 + 31) COMPUTE(kt & 1, kt << 6);

    __builtin_amdgcn_sched_barrier(0);
    asm volatile("s_waitcnt vmcnt(0)" ::: "memory");
    __builtin_amdgcn_s_barrier();
    __builtin_amdgcn_sched_barrier(0);
  }

  #pragma unroll
  for (int h = 0; h < 2; ++h) {
    float l = lpv[h][0] + lpv[h][1] + lpv[h][2] + lpv[h][3];
    l += __shfl_xor(l, 16, 64);
    l += __shfl_xor(l, 32, 64);
    const float inv = 1.0f / l;
    const int t = qrow0 + h * 16 + col;
    const size_t rowoff = ((size_t)b * T_ + t) * C_ + (size_t)hd * D_;
    #pragma unroll
    for (int mt = 0; mt < 4; ++mt) {
      f16x4 ov;
      #pragma unroll
      for (int r = 0; r < 4; ++r) ov[r] = (f16)(o[h][mt][r] * inv);
      *(f16x4*)&Aout[rowoff + mt * 16 + (g << 2)] = ov;
    }
  }
}

// ---------------- launch ----------------
extern "C" void kernel_launch(void* const* d_in, const int* in_sizes, int n_in,
                              void* d_out, int out_size, void* d_ws, size_t ws_size,
                              hipStream_t stream) {
  const float* x    = (const float*)d_in[0];
  const float* Wqkv = (const float*)d_in[1];
  const float* bqkv = (const float*)d_in[2];
  const float* Wout = (const float*)d_in[3];
  const float* bout = (const float*)d_in[4];
  float* out = (float*)d_out;

  char* ws = (char*)d_ws;
  f16* xb     = (f16*)ws;                   // 16MB (x in f16; later reused as Aout)
  f16* Wqkv_t = (f16*)(ws + (16u << 20));   // 6MB  [3072,1024]
  f16* Wout_t = (f16*)(ws + (22u << 20));   // 2MB  [1024,1024]
  f16* Qb     = (f16*)(ws + (24u << 20));   // 16MB [B,H,T,D]
  f16* Kb     = (f16*)(ws + (40u << 20));   // 16MB [B,H,T,D]
  f16* Vtb    = (f16*)(ws + (56u << 20));   // 16MB [B,H,D,T]

  dim3 gp(192, 32);
  prep_kernel<<<gp, 256, 0, stream>>>(x, xb, Wqkv, Wqkv_t, Wout, Wout_t);

  gemm_kernel<0><<<64 * 24, 256, 0, stream>>>(xb, Wqkv_t, bqkv, nullptr,
                                              Qb, Kb, Vtb, 8192, 3072, 1024);
  attn_kernel<<<1024, 256, 0, stream>>>(Qb, Kb, Vtb, xb /*Aout alias*/);
  gemm_kernel<1><<<64 * 8, 256, 0, stream>>>(xb, Wout_t, bout, out,
                                             nullptr, nullptr, nullptr, 8192, 1024, 1024);
}